// Round 8
// baseline (169.526 us; speedup 1.0000x reference)
//
#include <hip/hip_runtime.h>

// One timestep of the AI4CFD semicircle-cylinder NS solver.
// Grid: interior NY x NX = 160 x 6600, padded PY x PX = 162 x 6602.
// Round 8: round-7 PASSING structure, one change: CH 32->16 (core 16x40),
// doubling the jacobi grid to 1650 blocks (6.45/CU co-resident) and cutting
// the per-iteration serial row walk 3->2. Stencil body/BCs/loader unchanged.

namespace {
constexpr int NY = 160, NX = 6600, PY = 162, PX = 6602;
constexpr int NI = NY * NX;   // 1,056,000
constexpr int NP = PY * PX;   // 1,069,524
constexpr float DT  = 0.005f;
constexpr float NU  = 0.01f;          // 1/RE
constexpr float AT  = 1.0f / 70.0f;   // 1/(RE*PR)

constexpr int JK   = 8;               // iterations per stage
constexpr int HALO = 8;
constexpr int CW   = 40, CH = 16;     // core tile (per block output)
constexpr int TW   = CW + 2 * HALO;   // 56
constexpr int TH   = CH + 2 * HALO;   // 32
constexpr int TLW  = 60;              // LDS row stride (floats)
constexpr int BXN  = NX / CW;         // 165
constexpr int BYN  = NY / CH;         // 10
}

// Brinkman penalization field: semicircle at (x=1800, y=80), R=20, x>=1800.
__device__ __forceinline__ float sigma_at(int y, int x) {
    int ddx = x - 1800, ddy = y - 80;
    return ((ddx * ddx + ddy * ddy <= 400) && (x >= 1800)) ? 1.0e6f : 0.0f;
}

// ---- stencil weights ----
__device__ __forceinline__ float cxv(const float r[3][3]) {   // w_xadv
    return (r[0][0] - r[0][2] + 4.0f * (r[1][0] - r[1][2]) + r[2][0] - r[2][2])
           * (1.0f / 12.0f);
}
__device__ __forceinline__ float cyv(const float r[3][3]) {   // w_yadv
    return (r[0][0] + 4.0f * r[0][1] + r[0][2]
            - r[2][0] - 4.0f * r[2][1] - r[2][2]) * (1.0f / 12.0f);
}
__device__ __forceinline__ float cdv(const float r[3][3]) {   // w_diff
    return (r[0][0] + r[0][1] + r[0][2]
            + r[1][0] - 8.0f * r[1][1] + r[1][2]
            + r[2][0] + r[2][1] + r[2][2]) * (1.0f / 3.0f);
}

// g9 / g9p gathers for the aux kernels.
__device__ __forceinline__ void g9(const float* __restrict__ a, int y, int x,
                                   float lc, float r[3][3]) {
    int ym = max(y - 1, 0), yp = min(y + 1, NY - 1);
    int xp = min(x + 1, NX - 1);
    const float* r0 = a + (size_t)ym * NX;
    const float* r1 = a + (size_t)y  * NX;
    const float* r2 = a + (size_t)yp * NX;
    if (x == 0) { r[0][0] = lc; r[1][0] = lc; r[2][0] = lc; }
    else        { r[0][0] = r0[x-1]; r[1][0] = r1[x-1]; r[2][0] = r2[x-1]; }
    r[0][1] = r0[x]; r[0][2] = r0[xp];
    r[1][1] = r1[x]; r[1][2] = r1[xp];
    r[2][1] = r2[x]; r[2][2] = r2[xp];
}
__device__ __forceinline__ void g9p(const float* __restrict__ a, int y, int x,
                                    float r[3][3]) {
    int ym = max(y - 1, 0), yp = min(y + 1, NY - 1);
    int xm = max(x - 1, 0);
    bool rb = (x == NX - 1);
    const float* r0 = a + (size_t)ym * NX;
    const float* r1 = a + (size_t)y  * NX;
    const float* r2 = a + (size_t)yp * NX;
    r[0][0] = r0[xm]; r[0][1] = r0[x]; r[0][2] = rb ? 0.0f : r0[x+1];
    r[1][0] = r1[xm]; r[1][1] = r1[x]; r[1][2] = rb ? 0.0f : r1[x+1];
    r[2][0] = r2[xm]; r[2][1] = r2[x]; r[2][2] = rb ? 0.0f : r2[x+1];
}

// ---------------- aux kernels (unchanged, proven in rounds 1-3) ----------------
__global__ void pred_k(const float* __restrict__ u, const float* __restrict__ v,
                       const float* __restrict__ T,
                       float* __restrict__ up, float* __restrict__ vp,
                       float* __restrict__ Tp, float* __restrict__ oTT) {
    int px = blockIdx.x * blockDim.x + threadIdx.x;
    int py = blockIdx.y;
    if (px >= PX) return;
    int y = py - 1, x = px - 1;
    int cy = min(max(y, 0), NY - 1), cx = min(max(x, 0), NX - 1);
    oTT[(size_t)py * PX + px] = (px == 0) ? 0.0f : T[(size_t)cy * NX + cx];
    if (y < 0 || y >= NY || x < 0 || x >= NX) return;
    float ru[3][3], rv[3][3], rt[3][3];
    g9(u, y, x, 1.5f, ru);
    g9(v, y, x, 0.0f, rv);
    g9(T, y, x, 0.0f, rt);
    float uav = ru[1][1], vav = rv[1][1];
    float sig = sigma_at(y, x);
    const float hdt = 0.5f * DT;
    float un = ru[1][1] + hdt * (uav * cxv(ru) + vav * cyv(ru) + NU * cdv(ru));
    float vn = rv[1][1] + hdt * (uav * cxv(rv) + vav * cyv(rv) + NU * cdv(rv));
    float Tn = rt[1][1] + hdt * (uav * cxv(rt) + vav * cyv(rt) + AT * cdv(rt));
    float den = 1.0f + hdt * sig;
    un /= den; vn /= den;
    if (sig > 0.0f) Tn = 1.0f;
    size_t i = (size_t)y * NX + x;
    up[i] = un; vp[i] = vn; Tp[i] = Tn;
}

__global__ void corr_k(const float* __restrict__ u, const float* __restrict__ v,
                       const float* __restrict__ T,
                       const float* __restrict__ up, const float* __restrict__ vp,
                       const float* __restrict__ Tp,
                       float* __restrict__ us, float* __restrict__ vs,
                       float* __restrict__ oT,
                       float* __restrict__ obuu, float* __restrict__ obvv,
                       float* __restrict__ obTT) {
    int px = blockIdx.x * blockDim.x + threadIdx.x;
    int py = blockIdx.y;
    if (px >= PX) return;
    int y = py - 1, x = px - 1;
    int cy = min(max(y, 0), NY - 1), cx = min(max(x, 0), NX - 1);
    size_t o = (size_t)py * PX + px, s = (size_t)cy * NX + cx;
    obuu[o] = (px == 0) ? 1.5f : up[s];
    obvv[o] = (px == 0) ? 0.0f : vp[s];
    obTT[o] = (px == 0) ? 0.0f : Tp[s];
    if (y < 0 || y >= NY || x < 0 || x >= NX) return;
    float ru[3][3], rv[3][3], rt[3][3];
    g9(up, y, x, 1.5f, ru);
    g9(vp, y, x, 0.0f, rv);
    g9(Tp, y, x, 0.0f, rt);
    float uav = ru[1][1], vav = rv[1][1];
    float sig = sigma_at(y, x);
    size_t i = (size_t)y * NX + x;
    float un = u[i] + DT * (uav * cxv(ru) + vav * cyv(ru) + NU * cdv(ru));
    float vn = v[i] + DT * (uav * cxv(rv) + vav * cyv(rv) + NU * cdv(rv));
    float Tn = T[i] + DT * (uav * cxv(rt) + vav * cyv(rt) + AT * cdv(rt));
    float den = 1.0f + DT * sig;
    un /= den; vn /= den;
    if (sig > 0.0f) Tn = 1.0f;
    us[i] = un; vs[i] = vn; oT[i] = Tn;
}

__global__ void rhsdiv_k(const float* __restrict__ us, const float* __restrict__ vs,
                         float* __restrict__ rhs,
                         float* __restrict__ ouus, float* __restrict__ ovvs) {
    int px = blockIdx.x * blockDim.x + threadIdx.x;
    int py = blockIdx.y;
    if (px >= PX) return;
    int y = py - 1, x = px - 1;
    int cy = min(max(y, 0), NY - 1), cx = min(max(x, 0), NX - 1);
    size_t o = (size_t)py * PX + px, s = (size_t)cy * NX + cx;
    ouus[o] = (px == 0) ? 1.5f : us[s];
    ovvs[o] = (px == 0) ? 0.0f : vs[s];
    if (y < 0 || y >= NY || x < 0 || x >= NX) return;
    float ru[3][3], rv[3][3];
    g9(us, y, x, 1.5f, ru);
    g9(vs, y, x, 0.0f, rv);
    rhs[(size_t)y * NX + x] = (cxv(ru) + cyv(rv)) * (1.0f / DT);
}

__global__ void proj2_k(const float* __restrict__ us, const float* __restrict__ vs,
                        const float* __restrict__ p,
                        float* __restrict__ un, float* __restrict__ vn,
                        float* __restrict__ opp) {
    int px = blockIdx.x * blockDim.x + threadIdx.x;
    int py = blockIdx.y;
    if (px >= PX) return;
    int y = py - 1, x = px - 1;
    int cy = min(max(y, 0), NY - 1);
    opp[(size_t)py * PX + px] =
        (px == PX - 1) ? 0.0f : p[(size_t)cy * NX + max(x, 0)];
    if (y < 0 || y >= NY || x < 0 || x >= NX) return;
    float rp[3][3];
    g9p(p, y, x, rp);
    float sig = sigma_at(y, x);
    float den = 1.0f + DT * sig;
    size_t i = (size_t)y * NX + x;
    un[i] = (us[i] + cxv(rp) * DT) / den;
    vn[i] = (vs[i] + cyv(rp) * DT) / den;
}

// ---------------- fused Jacobi stage (round-7 body, 2 rows/thread) ----------
__device__ __forceinline__ void load_rhs_regs(const float* __restrict__ rhs,
                                              float4 (&rq)[2]) {
    const int tid = threadIdx.x;
    const int q = tid & 15, g = tid >> 4;
    const int gx0 = blockIdx.x * CW - HALO, gy0 = blockIdx.y * CH - HALO;
    const int r0 = 1 + 2 * g;
#pragma unroll
    for (int k = 0; k < 2; ++k) {
        int r = min(r0 + k, TH - 2);
        int cy = min(max(gy0 + r, 0), NY - 1);
        int cx = min(max(gx0 + 4 * q, 0), NX - 4);
        rq[k] = *(const float4*)(rhs + (size_t)cy * NX + cx);
    }
}

__global__ __launch_bounds__(256)
void jacobi_single(const float* __restrict__ src, const float* __restrict__ rhs,
                   float* __restrict__ dst, float* __restrict__ res) {
    __shared__ float pl[2][TH][TLW];   // 15.4 KB
    float4 rq[2];
    load_rhs_regs(rhs, rq);

    const int bx = blockIdx.x, by = blockIdx.y;
    const int tid = threadIdx.x;
    const int gx0 = bx * CW - HALO, gy0 = by * CH - HALO;

    // proven loader (scalar, clamped; east-of-domain zeros, both buffers)
    for (int i = tid; i < TH * TLW; i += 256) {
        int ly = i / TLW, lx = i - ly * TLW;
        float pv = 0.0f;
        int gx = gx0 + lx;
        if (lx < TW && gx < NX) {
            int cy = min(max(gy0 + ly, 0), NY - 1);
            pv = src[(size_t)cy * NX + max(gx, 0)];
        }
        pl[0][ly][lx] = pv;
        pl[1][ly][lx] = pv;
    }
    __syncthreads();

    const int q  = tid & 15;          // column quad
    const int g  = tid >> 4;          // row group
    const int lx0 = q * 4;
    const bool compute = (q < 14) && !((bx == BXN - 1) && (lx0 >= CW + HALO));
    const int r0 = 1 + 2 * g;         // rows 1..30 over 15 groups; g=15 idle
    const int r1 = min(r0 + 1, TH - 2);
    const bool wbc = (bx == 0) && (lx0 == HALO);      // cell gx==0: west = self
    const bool top = (by == 0), bot = (by == BYN - 1);
    const int lm = max(lx0 - 2, 0);
    const int lp = min(lx0 + 4, TW - 2);
    const bool wres = (res != nullptr);

    int cb = 0;
    for (int j = 0; j < JK; ++j) {
        const bool last_it = (j == JK - 1);
        float (*cur)[TLW] = pl[cb];
        float (*nxt)[TLW] = pl[cb ^ 1];
        float aL, aR, bL, bR, cL, cR;
        float4 aC, bC, cC;
        auto ld = [&](int rr, float& L, float4& C, float& R) {
            const float* row = &cur[rr][0];
            float2 lo = *(const float2*)(row + lm);
            C = *(const float4*)(row + lx0);
            float2 hi = *(const float2*)(row + lp);
            L = wbc ? C.x : lo.y;
            R = hi.x;
        };
        ld(r0 - 1, aL, aC, aR);
        ld(min(r0, TH - 1), bL, bC, bR);
        for (int k = 0; k < 2; ++k) {
            const int r = r0 + k;
            if (r <= r1) {
                ld(r + 1, cL, cC, cR);
                bool nbc = top && (r == HALO);           // gy==0: north = self
                bool sbc = bot && (r == HALO + CH - 1);  // gy==NY-1: south = self
                float  nL = nbc ? bL : aL, nR = nbc ? bR : aR;
                float4 nC = nbc ? bC : aC;
                float  sL = sbc ? bL : cL, sR = sbc ? bR : cR;
                float4 sC = sbc ? bC : cC;
                float s0 = nL   + nC.x + nC.y + bL   + bC.y + sL   + sC.x + sC.y;
                float s1 = nC.x + nC.y + nC.z + bC.x + bC.z + sC.x + sC.y + sC.z;
                float s2 = nC.y + nC.z + nC.w + bC.y + bC.w + sC.y + sC.z + sC.w;
                float s3 = nC.z + nC.w + nR   + bC.z + bR   + sC.z + sC.w + sR;
                float e0 = (8.0f * bC.x - s0) * (1.0f / 3.0f) - rq[k].x;
                float e1 = (8.0f * bC.y - s1) * (1.0f / 3.0f) - rq[k].y;
                float e2 = (8.0f * bC.z - s2) * (1.0f / 3.0f) - rq[k].z;
                float e3 = (8.0f * bC.w - s3) * (1.0f / 3.0f) - rq[k].w;
                float4 pn = make_float4(bC.x - 0.375f * e0, bC.y - 0.375f * e1,
                                        bC.z - 0.375f * e2, bC.w - 0.375f * e3);
                if (last_it) {
                    // direct global store of core cells (each exactly once)
                    if (compute && r >= HALO && r < HALO + CH &&
                        lx0 >= HALO && lx0 < HALO + CW) {
                        size_t o = (size_t)(gy0 + r) * NX + (gx0 + lx0);
                        *(float4*)(dst + o) = pn;
                        if (wres) {
                            float4 e4 = make_float4(e0, e1, e2, e3);
                            *(float4*)(res + o) = e4;
                        }
                    }
                } else if (compute) {
                    *(float4*)(&nxt[r][lx0]) = pn;
                }
                aL = bL; aC = bC; aR = bR;
                bL = cL; bC = cC; bR = cR;
            }
        }
        cb ^= 1;
        __syncthreads();
    }
}

extern "C" void kernel_launch(void* const* d_in, const int* in_sizes, int n_in,
                              void* d_out, int out_size, void* d_ws, size_t ws_size,
                              hipStream_t stream) {
    const float* u = (const float*)d_in[0];
    const float* v = (const float*)d_in[1];
    const float* p = (const float*)d_in[2];
    const float* T = (const float*)d_in[3];

    float* out = (float*)d_out;
    float* o_u   = out;
    float* o_v   = out + (size_t)NI;
    float* o_p   = out + 2 * (size_t)NI;
    float* o_T   = out + 3 * (size_t)NI;
    float* o_uus = out + 4 * (size_t)NI;
    float* o_vvs = o_uus + (size_t)NP;
    float* o_pp  = o_uus + 2 * (size_t)NP;
    float* o_TT  = o_uus + 3 * (size_t)NP;
    float* o_buu = o_uus + 4 * (size_t)NP;
    float* o_bvv = o_uus + 5 * (size_t)NP;
    float* o_bTT = o_uus + 6 * (size_t)NP;
    float* o_res = o_uus + 7 * (size_t)NP;

    float* w  = (float*)d_ws;
    float* s_up  = w;                      // u_pred -> jacobi ping A
    float* s_vp  = w + (size_t)NI;         // v_pred -> jacobi ping B
    float* s_Tp  = w + 2 * (size_t)NI;     // T_pred -> rhs
    float* s_us  = w + 3 * (size_t)NI;     // u_star
    float* s_vs  = w + 4 * (size_t)NI;     // v_star
    float* s_rhs = s_Tp;
    float* pA = s_up;
    float* pB = s_vp;

    dim3 blk(256, 1, 1);
    dim3 gp((PX + 255) / 256, PY, 1);
    dim3 gj(BXN, BYN, 1);

    pred_k<<<gp, blk, 0, stream>>>(u, v, T, s_up, s_vp, s_Tp, o_TT);
    corr_k<<<gp, blk, 0, stream>>>(u, v, T, s_up, s_vp, s_Tp,
                                   s_us, s_vs, o_T, o_buu, o_bvv, o_bTT);
    rhsdiv_k<<<gp, blk, 0, stream>>>(s_us, s_vs, s_rhs, o_uus, o_vvs);

    // 40 Jacobi iterations = 5 stream-ordered launches x 8 fused iters
    jacobi_single<<<gj, blk, 0, stream>>>(p,  s_rhs, pA,  nullptr);
    jacobi_single<<<gj, blk, 0, stream>>>(pA, s_rhs, pB,  nullptr);
    jacobi_single<<<gj, blk, 0, stream>>>(pB, s_rhs, pA,  nullptr);
    jacobi_single<<<gj, blk, 0, stream>>>(pA, s_rhs, pB,  nullptr);
    jacobi_single<<<gj, blk, 0, stream>>>(pB, s_rhs, o_p, o_res);

    proj2_k<<<gp, blk, 0, stream>>>(s_us, s_vs, o_p, o_u, o_v, o_pp);
}

// Round 9
// 132.198 us; speedup vs baseline: 1.2824x; 1.2824x over previous
//
#include <hip/hip_runtime.h>

// One timestep of the AI4CFD semicircle-cylinder NS solver.
// Grid: interior NY x NX = 160 x 6600, padded PY x PX = 162 x 6602.
// Round 9: register-resident Jacobi. One wave owns a 64x36 tile entirely in
// VGPRs (lane = column, rows = registers). W/E neighbors via __shfl_up/down,
// N/S via own registers. No LDS tile, no __syncthreads, no ping-pong.
// 5 stream-ordered launches x 8 iterations. Aux kernels unchanged (proven).

namespace {
constexpr int NY = 160, NX = 6600, PY = 162, PX = 6602;
constexpr int NI = NY * NX;   // 1,056,000
constexpr int NP = PY * PX;   // 1,069,524
constexpr float DT  = 0.005f;
constexpr float NU  = 0.01f;          // 1/RE
constexpr float AT  = 1.0f / 70.0f;   // 1/(RE*PR)

constexpr int JK   = 8;               // iterations per stage
constexpr int HALO = 8;
constexpr int JCH  = 20;              // core rows per wave
constexpr int JCW  = 48;              // core cols per wave (64 - 2*HALO)
constexpr int JR   = JCH + 2 * HALO;  // 36 register rows
constexpr int JTX  = (NX + JCW - 1) / JCW;  // 138 (last tile partially OOB)
constexpr int JTY  = NY / JCH;        // 8
constexpr int JWAVES = JTX * JTY;     // 1104
}

// Brinkman penalization field: semicircle at (x=1800, y=80), R=20, x>=1800.
__device__ __forceinline__ float sigma_at(int y, int x) {
    int ddx = x - 1800, ddy = y - 80;
    return ((ddx * ddx + ddy * ddy <= 400) && (x >= 1800)) ? 1.0e6f : 0.0f;
}

// ---- stencil weights ----
__device__ __forceinline__ float cxv(const float r[3][3]) {   // w_xadv
    return (r[0][0] - r[0][2] + 4.0f * (r[1][0] - r[1][2]) + r[2][0] - r[2][2])
           * (1.0f / 12.0f);
}
__device__ __forceinline__ float cyv(const float r[3][3]) {   // w_yadv
    return (r[0][0] + 4.0f * r[0][1] + r[0][2]
            - r[2][0] - 4.0f * r[2][1] - r[2][2]) * (1.0f / 12.0f);
}
__device__ __forceinline__ float cdv(const float r[3][3]) {   // w_diff
    return (r[0][0] + r[0][1] + r[0][2]
            + r[1][0] - 8.0f * r[1][1] + r[1][2]
            + r[2][0] + r[2][1] + r[2][2]) * (1.0f / 3.0f);
}

// g9 / g9p gathers for the aux kernels.
__device__ __forceinline__ void g9(const float* __restrict__ a, int y, int x,
                                   float lc, float r[3][3]) {
    int ym = max(y - 1, 0), yp = min(y + 1, NY - 1);
    int xp = min(x + 1, NX - 1);
    const float* r0 = a + (size_t)ym * NX;
    const float* r1 = a + (size_t)y  * NX;
    const float* r2 = a + (size_t)yp * NX;
    if (x == 0) { r[0][0] = lc; r[1][0] = lc; r[2][0] = lc; }
    else        { r[0][0] = r0[x-1]; r[1][0] = r1[x-1]; r[2][0] = r2[x-1]; }
    r[0][1] = r0[x]; r[0][2] = r0[xp];
    r[1][1] = r1[x]; r[1][2] = r1[xp];
    r[2][1] = r2[x]; r[2][2] = r2[xp];
}
__device__ __forceinline__ void g9p(const float* __restrict__ a, int y, int x,
                                    float r[3][3]) {
    int ym = max(y - 1, 0), yp = min(y + 1, NY - 1);
    int xm = max(x - 1, 0);
    bool rb = (x == NX - 1);
    const float* r0 = a + (size_t)ym * NX;
    const float* r1 = a + (size_t)y  * NX;
    const float* r2 = a + (size_t)yp * NX;
    r[0][0] = r0[xm]; r[0][1] = r0[x]; r[0][2] = rb ? 0.0f : r0[x+1];
    r[1][0] = r1[xm]; r[1][1] = r1[x]; r[1][2] = rb ? 0.0f : r1[x+1];
    r[2][0] = r2[xm]; r[2][1] = r2[x]; r[2][2] = rb ? 0.0f : r2[x+1];
}

// ---------------- aux kernels (unchanged, proven in rounds 1-3/7) --------------
__global__ void pred_k(const float* __restrict__ u, const float* __restrict__ v,
                       const float* __restrict__ T,
                       float* __restrict__ up, float* __restrict__ vp,
                       float* __restrict__ Tp, float* __restrict__ oTT) {
    int px = blockIdx.x * blockDim.x + threadIdx.x;
    int py = blockIdx.y;
    if (px >= PX) return;
    int y = py - 1, x = px - 1;
    int cy = min(max(y, 0), NY - 1), cx = min(max(x, 0), NX - 1);
    oTT[(size_t)py * PX + px] = (px == 0) ? 0.0f : T[(size_t)cy * NX + cx];
    if (y < 0 || y >= NY || x < 0 || x >= NX) return;
    float ru[3][3], rv[3][3], rt[3][3];
    g9(u, y, x, 1.5f, ru);
    g9(v, y, x, 0.0f, rv);
    g9(T, y, x, 0.0f, rt);
    float uav = ru[1][1], vav = rv[1][1];
    float sig = sigma_at(y, x);
    const float hdt = 0.5f * DT;
    float un = ru[1][1] + hdt * (uav * cxv(ru) + vav * cyv(ru) + NU * cdv(ru));
    float vn = rv[1][1] + hdt * (uav * cxv(rv) + vav * cyv(rv) + NU * cdv(rv));
    float Tn = rt[1][1] + hdt * (uav * cxv(rt) + vav * cyv(rt) + AT * cdv(rt));
    float den = 1.0f + hdt * sig;
    un /= den; vn /= den;
    if (sig > 0.0f) Tn = 1.0f;
    size_t i = (size_t)y * NX + x;
    up[i] = un; vp[i] = vn; Tp[i] = Tn;
}

__global__ void corr_k(const float* __restrict__ u, const float* __restrict__ v,
                       const float* __restrict__ T,
                       const float* __restrict__ up, const float* __restrict__ vp,
                       const float* __restrict__ Tp,
                       float* __restrict__ us, float* __restrict__ vs,
                       float* __restrict__ oT,
                       float* __restrict__ obuu, float* __restrict__ obvv,
                       float* __restrict__ obTT) {
    int px = blockIdx.x * blockDim.x + threadIdx.x;
    int py = blockIdx.y;
    if (px >= PX) return;
    int y = py - 1, x = px - 1;
    int cy = min(max(y, 0), NY - 1), cx = min(max(x, 0), NX - 1);
    size_t o = (size_t)py * PX + px, s = (size_t)cy * NX + cx;
    obuu[o] = (px == 0) ? 1.5f : up[s];
    obvv[o] = (px == 0) ? 0.0f : vp[s];
    obTT[o] = (px == 0) ? 0.0f : Tp[s];
    if (y < 0 || y >= NY || x < 0 || x >= NX) return;
    float ru[3][3], rv[3][3], rt[3][3];
    g9(up, y, x, 1.5f, ru);
    g9(vp, y, x, 0.0f, rv);
    g9(Tp, y, x, 0.0f, rt);
    float uav = ru[1][1], vav = rv[1][1];
    float sig = sigma_at(y, x);
    size_t i = (size_t)y * NX + x;
    float un = u[i] + DT * (uav * cxv(ru) + vav * cyv(ru) + NU * cdv(ru));
    float vn = v[i] + DT * (uav * cxv(rv) + vav * cyv(rv) + NU * cdv(rv));
    float Tn = T[i] + DT * (uav * cxv(rt) + vav * cyv(rt) + AT * cdv(rt));
    float den = 1.0f + DT * sig;
    un /= den; vn /= den;
    if (sig > 0.0f) Tn = 1.0f;
    us[i] = un; vs[i] = vn; oT[i] = Tn;
}

__global__ void rhsdiv_k(const float* __restrict__ us, const float* __restrict__ vs,
                         float* __restrict__ rhs,
                         float* __restrict__ ouus, float* __restrict__ ovvs) {
    int px = blockIdx.x * blockDim.x + threadIdx.x;
    int py = blockIdx.y;
    if (px >= PX) return;
    int y = py - 1, x = px - 1;
    int cy = min(max(y, 0), NY - 1), cx = min(max(x, 0), NX - 1);
    size_t o = (size_t)py * PX + px, s = (size_t)cy * NX + cx;
    ouus[o] = (px == 0) ? 1.5f : us[s];
    ovvs[o] = (px == 0) ? 0.0f : vs[s];
    if (y < 0 || y >= NY || x < 0 || x >= NX) return;
    float ru[3][3], rv[3][3];
    g9(us, y, x, 1.5f, ru);
    g9(vs, y, x, 0.0f, rv);
    rhs[(size_t)y * NX + x] = (cxv(ru) + cyv(rv)) * (1.0f / DT);
}

__global__ void proj2_k(const float* __restrict__ us, const float* __restrict__ vs,
                        const float* __restrict__ p,
                        float* __restrict__ un, float* __restrict__ vn,
                        float* __restrict__ opp) {
    int px = blockIdx.x * blockDim.x + threadIdx.x;
    int py = blockIdx.y;
    if (px >= PX) return;
    int y = py - 1, x = px - 1;
    int cy = min(max(y, 0), NY - 1);
    opp[(size_t)py * PX + px] =
        (px == PX - 1) ? 0.0f : p[(size_t)cy * NX + max(x, 0)];
    if (y < 0 || y >= NY || x < 0 || x >= NX) return;
    float rp[3][3];
    g9p(p, y, x, rp);
    float sig = sigma_at(y, x);
    float den = 1.0f + DT * sig;
    size_t i = (size_t)y * NX + x;
    un[i] = (us[i] + cxv(rp) * DT) / den;
    vn[i] = (vs[i] + cyv(rp) * DT) / den;
}

// ---------------- register-resident Jacobi ----------------
// Horizontal colsum of one row value with pressure BCs:
//   west of col 0 = self (edge clamp), east of col NX-1 = 0 (outlet).
__device__ __forceinline__ float colsum(float c, bool wb, bool eb) {
    float w = __shfl_up(c, 1, 64);
    float e = __shfl_down(c, 1, 64);
    w = wb ? c : w;
    e = eb ? 0.0f : e;
    return w + c + e;
}

// One Jacobi sweep over the register tile. EMIT: store residual (last stage,
// last iteration) for core cells.
template <bool EMIT>
__device__ __forceinline__ void jsweep(float (&p)[JR], const float (&rq)[JR - 2],
                                       int gy0, int gx, bool wb, bool eb,
                                       bool stp, float* __restrict__ res) {
    float csm = colsum(p[0], wb, eb);
    float csc = colsum(p[1], wb, eb);
#pragma unroll
    for (int r = 1; r < JR - 1; ++r) {
        float csp = colsum(p[r + 1], wb, eb);
        // domain-edge BC: north/south neighbor row = self row (edge clamp)
        float na = (gy0 + r == 0)      ? csc : csm;
        float sa = (gy0 + r == NY - 1) ? csc : csp;
        float sum9 = na + csc + sa;
        float e = 3.0f * p[r] - sum9 * (1.0f / 3.0f) - rq[r - 1];
        if (EMIT) {
            if (r >= HALO && r < HALO + JCH && stp)
                res[(size_t)(gy0 + r) * NX + gx] = e;
        }
        p[r] = p[r] - 0.375f * e;   // 1/DIAG = 3/8
        csm = csc; csc = csp;
    }
}

__global__ __launch_bounds__(64)
void jacobi_reg(const float* __restrict__ src, const float* __restrict__ rhs,
                float* __restrict__ dst, float* __restrict__ res) {
    const int wid = blockIdx.x;               // one 64-lane wave per block
    const int tx = wid % JTX, ty = wid / JTX;
    const int lane = threadIdx.x;             // 0..63
    const int gx = tx * JCW - HALO + lane;    // this lane's column
    const int gy0 = ty * JCH - HALO;          // tile top row
    const int cgx = min(max(gx, 0), NX - 1);  // clamped load column
    const bool wb = (gx == 0);                // west domain edge (clamp)
    const bool eb = (gx == NX - 1);           // east domain edge (outlet 0)
    const bool stp = (lane >= HALO) && (lane < HALO + JCW) && (gx < NX);

    float p[JR];
    float rq[JR - 2];
#pragma unroll
    for (int r = 0; r < JR; ++r) {
        int cy = min(max(gy0 + r, 0), NY - 1);
        p[r] = src[(size_t)cy * NX + cgx];
    }
#pragma unroll
    for (int r = 1; r < JR - 1; ++r) {
        int cy = min(max(gy0 + r, 0), NY - 1);
        rq[r - 1] = rhs[(size_t)cy * NX + cgx];
    }

#pragma unroll 1
    for (int j = 0; j < JK - 1; ++j)
        jsweep<false>(p, rq, gy0, gx, wb, eb, stp, res);
    if (res) jsweep<true>(p, rq, gy0, gx, wb, eb, stp, res);
    else     jsweep<false>(p, rq, gy0, gx, wb, eb, stp, res);

    // store core (rows HALO..HALO+JCH-1, core columns only)
    if (stp) {
#pragma unroll
        for (int r = HALO; r < HALO + JCH; ++r)
            dst[(size_t)(gy0 + r) * NX + gx] = p[r];
    }
}

extern "C" void kernel_launch(void* const* d_in, const int* in_sizes, int n_in,
                              void* d_out, int out_size, void* d_ws, size_t ws_size,
                              hipStream_t stream) {
    const float* u = (const float*)d_in[0];
    const float* v = (const float*)d_in[1];
    const float* p = (const float*)d_in[2];
    const float* T = (const float*)d_in[3];

    float* out = (float*)d_out;
    float* o_u   = out;
    float* o_v   = out + (size_t)NI;
    float* o_p   = out + 2 * (size_t)NI;
    float* o_T   = out + 3 * (size_t)NI;
    float* o_uus = out + 4 * (size_t)NI;
    float* o_vvs = o_uus + (size_t)NP;
    float* o_pp  = o_uus + 2 * (size_t)NP;
    float* o_TT  = o_uus + 3 * (size_t)NP;
    float* o_buu = o_uus + 4 * (size_t)NP;
    float* o_bvv = o_uus + 5 * (size_t)NP;
    float* o_bTT = o_uus + 6 * (size_t)NP;
    float* o_res = o_uus + 7 * (size_t)NP;

    float* w  = (float*)d_ws;
    float* s_up  = w;                      // u_pred -> jacobi ping A
    float* s_vp  = w + (size_t)NI;         // v_pred -> jacobi ping B
    float* s_Tp  = w + 2 * (size_t)NI;     // T_pred -> rhs
    float* s_us  = w + 3 * (size_t)NI;     // u_star
    float* s_vs  = w + 4 * (size_t)NI;     // v_star
    float* s_rhs = s_Tp;
    float* pA = s_up;
    float* pB = s_vp;

    dim3 blk(256, 1, 1);
    dim3 gp((PX + 255) / 256, PY, 1);
    dim3 gj(JWAVES, 1, 1);
    dim3 bj(64, 1, 1);

    pred_k<<<gp, blk, 0, stream>>>(u, v, T, s_up, s_vp, s_Tp, o_TT);
    corr_k<<<gp, blk, 0, stream>>>(u, v, T, s_up, s_vp, s_Tp,
                                   s_us, s_vs, o_T, o_buu, o_bvv, o_bTT);
    rhsdiv_k<<<gp, blk, 0, stream>>>(s_us, s_vs, s_rhs, o_uus, o_vvs);

    // 40 Jacobi iterations = 5 stream-ordered launches x 8 register-resident
    jacobi_reg<<<gj, bj, 0, stream>>>(p,  s_rhs, pA,  nullptr);
    jacobi_reg<<<gj, bj, 0, stream>>>(pA, s_rhs, pB,  nullptr);
    jacobi_reg<<<gj, bj, 0, stream>>>(pB, s_rhs, pA,  nullptr);
    jacobi_reg<<<gj, bj, 0, stream>>>(pA, s_rhs, pB,  nullptr);
    jacobi_reg<<<gj, bj, 0, stream>>>(pB, s_rhs, o_p, o_res);

    proj2_k<<<gp, blk, 0, stream>>>(s_us, s_vs, o_p, o_u, o_v, o_pp);
}